// Round 8
// baseline (545.002 us; speedup 1.0000x reference)
//
#include <hip/hip_runtime.h>
#include <math.h>

// Problem constants (fixed by the reference)
#define N_NODES 50000
#define E_EDGES 1600000
#define R_REL   50
#define B_BAS   30
#define H_DIM   16
#define C_DIM   4
#define NH      (N_NODES * H_DIM)
#define NH4     (NH / 4)                 // 200,000 float4 columns

// dst slicing for XCD-local scatter writes in k_bucket
#define NSLICE      8
#define SLICE_NODES (N_NODES / NSLICE)   // 6250

// k_front geometry: 800 blocks x 256 threads; each thread owns 4 consecutive
// (n,h) columns (float4), each block additionally histograms 2000 edges.
#define FRONT_BLOCKS    800
#define EDGES_PER_BLOCK (E_EDGES / FRONT_BLOCKS)  // 2000

// ---------------------------------------------------------------------------
// k_front: fused w1 precompute + dst histogram.
//   w1[r][n][h] = sum_b comp1[r][b]*basis1[b][n][h]
// float4 end-to-end: 30 global_load_dwordx4 + 50 global_store_dwordx4 per
// thread (round-7 scalar version: 256B/wave-inst -> only 2.6 TB/s; dwordx4
// gives 1KB/wave-inst, the m13-style streaming sweet spot).
// comp1 read directly (thread-uniform -> s_load, SGPR operand to v_fmac).
// ---------------------------------------------------------------------------
__global__ __launch_bounds__(256) void k_front(const float* __restrict__ basis1,
                                               const float* __restrict__ comp1,
                                               float* __restrict__ w1,
                                               const int* __restrict__ ei,
                                               int* __restrict__ cnt_i) {
    // ---- histogram share: fire-and-forget atomics, 2000 edges/block ----
    {
        const int ebase = blockIdx.x * EDGES_PER_BLOCK;
#pragma unroll
        for (int i = 0; i < 8; ++i) {
            const int el = threadIdx.x + i * 256;
            if (el < EDGES_PER_BLOCK)
                atomicAdd(&cnt_i[ei[E_EDGES + ebase + el]], 1);
        }
    }

    // ---- w1 share: one float4 column-group per thread ----
    const int idx4 = blockIdx.x * 256 + threadIdx.x;
    if (idx4 >= NH4) return;

    float4 bv[B_BAS];
#pragma unroll
    for (int b = 0; b < B_BAS; ++b)
        bv[b] = *(const float4*)(basis1 + (size_t)b * NH + idx4 * 4);

    for (int r = 0; r < R_REL; ++r) {
        float4 acc = {0.f, 0.f, 0.f, 0.f};
#pragma unroll
        for (int b = 0; b < B_BAS; ++b) {
            const float c = comp1[r * B_BAS + b];
            acc.x += c * bv[b].x;
            acc.y += c * bv[b].y;
            acc.z += c * bv[b].z;
            acc.w += c * bv[b].w;
        }
        *(float4*)(w1 + (size_t)r * NH + idx4 * 4) = acc;
    }
}

// ---------------------------------------------------------------------------
// k_scan: whole CSR offset build in ONE block (1024 threads).
// Each thread owns 49 consecutive nodes (1024*49 = 50176 >= 50000):
// sequential local scan -> block scan of per-thread sums -> write off+cursor.
// w2 (tiny, independent) piggybacks at the end.
// Replaces 3 kernels (scan_part/scan_tops/scan_add) -> fewer dispatch drains.
// ---------------------------------------------------------------------------
#define SCAN_ITEMS 49

__global__ __launch_bounds__(1024) void k_scan(const int* __restrict__ cnt_i,
                                               int* __restrict__ off,
                                               int* __restrict__ cursor,
                                               const float* __restrict__ basis2,
                                               const float* __restrict__ comp2,
                                               float* __restrict__ w2) {
    const int t = threadIdx.x;
    const int lane = t & 63;
    const int wid = t >> 6;          // 16 waves
    const int base = t * SCAN_ITEMS;

    int loc[SCAN_ITEMS];
    int sum = 0;
#pragma unroll
    for (int i = 0; i < SCAN_ITEMS; ++i) {
        const int idx = base + i;
        const int v = (idx < N_NODES) ? cnt_i[idx] : 0;
        loc[i] = sum;
        sum += v;
    }

    // inclusive wave scan of per-thread sums
    int s = sum;
#pragma unroll
    for (int d = 1; d < 64; d <<= 1) {
        const int tv = __shfl_up(s, d, 64);
        if (lane >= d) s += tv;
    }
    __shared__ int wsum[16];
    if (lane == 63) wsum[wid] = s;
    __syncthreads();
    int woff = 0;
    for (int w = 0; w < wid; ++w) woff += wsum[w];
    const int prefix = woff + s - sum;   // exclusive prefix for this thread

#pragma unroll
    for (int i = 0; i < SCAN_ITEMS; ++i) {
        const int idx = base + i;
        if (idx < N_NODES) {
            const int o = prefix + loc[i];
            off[idx] = o;
            cursor[idx] = o;
        }
    }
    if (t == 0) off[N_NODES] = E_EDGES;

    // w2[r][h][c] = sum_b comp2[r][b] * basis2[b][h][c]   (3200 outputs)
    const int HC = H_DIM * C_DIM;  // 64
    for (int idx = t; idx < R_REL * HC; idx += 1024) {
        const int r = idx / HC;
        const int hc = idx % HC;
        float acc = 0.f;
#pragma unroll
        for (int b = 0; b < B_BAS; ++b)
            acc += comp2[r * B_BAS + b] * basis2[b * HC + hc];
        w2[idx] = acc;
    }
}

// ---------------------------------------------------------------------------
// CSR build step 3 (XCD-sliced): scatter packed (src | et<<16) records into
// dst buckets. blockIdx = chunk*8 + slice; a block only handles edges whose
// dst is in its slice's 6250-node range (blockIdx%8 ~ XCD -> rec slice writes
// coalesce in one XCD's L2). Streaming ei/et reads are non-temporal so they
// don't evict the dirty rec lines before neighbors coalesce into them.
// ---------------------------------------------------------------------------
__global__ __launch_bounds__(256) void k_bucket(const int* __restrict__ ei,
                                                const int* __restrict__ et,
                                                int* __restrict__ cursor,
                                                unsigned* __restrict__ rec) {
    const int chunk = blockIdx.x >> 3;
    const int slice = blockIdx.x & (NSLICE - 1);
    const int lo = slice * SLICE_NODES;

    const int e = chunk * 256 + threadIdx.x;
    if (e >= E_EDGES) return;
    const int dst = __builtin_nontemporal_load(&ei[E_EDGES + e]);
    if ((unsigned)(dst - lo) >= (unsigned)SLICE_NODES) return;

    const int src = __builtin_nontemporal_load(&ei[e]);
    const int r = __builtin_nontemporal_load(&et[e]);
    const int pos = atomicAdd(&cursor[dst], 1);
    rec[pos] = (unsigned)src | ((unsigned)r << 16);
}

// ---------------------------------------------------------------------------
// k_agg1x: atomic-free layer-1 aggregation fused with x-epilogue.
// One wave per dst; lanes = (sub=lane>>4) edge-slot x (h=lane&15).
// x[dst][h] = relu( mean_e w1[et][src][h] + root1 + bias1 )
// ---------------------------------------------------------------------------
__global__ __launch_bounds__(256) void k_agg1x(const unsigned* __restrict__ rec,
                                               const int* __restrict__ off,
                                               const float* __restrict__ w1,
                                               const float* __restrict__ root1,
                                               const float* __restrict__ bias1,
                                               float* __restrict__ x) {
    const int wid = threadIdx.x >> 6;
    const int lane = threadIdx.x & 63;
    const int dst = blockIdx.x * 4 + wid;   // grid = 12500, 4 waves/block
    const int h = lane & 15;
    const int sub = lane >> 4;
    const int e0 = off[dst], e1 = off[dst + 1];

    float acc = 0.f;
    for (int e = e0 + sub; e < e1; e += 4) {
        const unsigned p = rec[e];
        const int src = (int)(p & 0xFFFFu);
        const int r = (int)(p >> 16);
        acc += w1[(size_t)r * NH + src * H_DIM + h];
    }
    acc += __shfl_xor(acc, 16, 64);
    acc += __shfl_xor(acc, 32, 64);

    if (sub == 0) {
        const float c = fmaxf((float)(e1 - e0), 1.f);
        const float v = acc / c + root1[dst * H_DIM + h] + bias1[h];
        x[dst * H_DIM + h] = fmaxf(v, 0.f);
    }
}

// ---------------------------------------------------------------------------
// k_agg2out: atomic-free layer-2 aggregation fused with root2 matvec and
// log_softmax. One wave per dst; per edge-slot 16 lanes each do 4 FMAs.
// ---------------------------------------------------------------------------
__global__ __launch_bounds__(256) void k_agg2out(const unsigned* __restrict__ rec,
                                                 const int* __restrict__ off,
                                                 const float* __restrict__ x,
                                                 const float* __restrict__ w2,
                                                 const float* __restrict__ root2,
                                                 const float* __restrict__ bias2,
                                                 float* __restrict__ out) {
    const int wid = threadIdx.x >> 6;
    const int lane = threadIdx.x & 63;
    const int dst = blockIdx.x * 4 + wid;
    const int h = lane & 15;
    const int sub = lane >> 4;
    const int e0 = off[dst], e1 = off[dst + 1];

    float a0 = 0.f, a1 = 0.f, a2 = 0.f, a3 = 0.f;
    for (int e = e0 + sub; e < e1; e += 4) {
        const unsigned p = rec[e];
        const int src = (int)(p & 0xFFFFu);
        const int r = (int)(p >> 16);
        const float xv = x[src * H_DIM + h];
        const float4 w = *(const float4*)(w2 + r * (H_DIM * C_DIM) + h * C_DIM);
        a0 += xv * w.x; a1 += xv * w.y; a2 += xv * w.z; a3 += xv * w.w;
    }
    // reduce over all 64 lanes (sums over both h and edge-slot)
#pragma unroll
    for (int d = 1; d < 64; d <<= 1) {
        a0 += __shfl_xor(a0, d, 64);
        a1 += __shfl_xor(a1, d, 64);
        a2 += __shfl_xor(a2, d, 64);
        a3 += __shfl_xor(a3, d, 64);
    }

    if (lane == 0) {
        const float c = fmaxf((float)(e1 - e0), 1.f);
        float y0 = a0 / c + bias2[0];
        float y1 = a1 / c + bias2[1];
        float y2 = a2 / c + bias2[2];
        float y3 = a3 / c + bias2[3];
#pragma unroll
        for (int hh = 0; hh < H_DIM; ++hh) {
            const float xv = x[dst * H_DIM + hh];
            const float4 w = *(const float4*)(root2 + hh * C_DIM);
            y0 += xv * w.x; y1 += xv * w.y; y2 += xv * w.z; y3 += xv * w.w;
        }
        const float m = fmaxf(fmaxf(y0, y1), fmaxf(y2, y3));
        const float s = expf(y0 - m) + expf(y1 - m) + expf(y2 - m) + expf(y3 - m);
        const float lse = m + logf(s);
        out[dst * 4 + 0] = y0 - lse;
        out[dst * 4 + 1] = y1 - lse;
        out[dst * 4 + 2] = y2 - lse;
        out[dst * 4 + 3] = y3 - lse;
    }
}

// ---------------------------------------------------------------------------
extern "C" void kernel_launch(void* const* d_in, const int* in_sizes, int n_in,
                              void* d_out, int out_size, void* d_ws, size_t ws_size,
                              hipStream_t stream) {
    const int*   edge_index = (const int*)d_in[0];   // [2, E]
    const int*   edge_type  = (const int*)d_in[1];   // [E]
    // d_in[2] = edge_norm (unused by reference)
    const float* basis1 = (const float*)d_in[3];     // [B, N, H]
    const float* comp1  = (const float*)d_in[4];     // [R, B]
    const float* root1  = (const float*)d_in[5];     // [N, H]
    const float* bias1  = (const float*)d_in[6];     // [H]
    const float* basis2 = (const float*)d_in[7];     // [B, H, C]
    const float* comp2  = (const float*)d_in[8];     // [R, B]
    const float* root2  = (const float*)d_in[9];     // [H, C]
    const float* bias2  = (const float*)d_in[10];    // [C]

    float* out = (float*)d_out;

    // ---- workspace layout (16B aligned blocks) ----
    char* ws = (char*)d_ws;
    size_t o = 0;
    auto take = [&](size_t bytes) { char* p = ws + o; o += (bytes + 15) & ~(size_t)15; return p; };

    float*    w1     = (float*)   take((size_t)R_REL * NH * sizeof(float));   // 160.0 MB
    unsigned* rec    = (unsigned*)take((size_t)E_EDGES * sizeof(unsigned));   //   6.4 MB
    float*    x      = (float*)   take((size_t)NH * sizeof(float));           //   3.2 MB
    int*      off    = (int*)     take((size_t)(N_NODES + 1) * sizeof(int));
    int*      cnt_i  = (int*)     take((size_t)N_NODES * sizeof(int));
    int*      cursor = (int*)     take((size_t)N_NODES * sizeof(int));
    float*    w2     = (float*)   take((size_t)R_REL * H_DIM * C_DIM * sizeof(float));
    (void)ws_size;

    // zero the histogram (ws is poisoned 0xAA before every timed call)
    hipMemsetAsync(cnt_i, 0, (size_t)N_NODES * sizeof(int), stream);

    // fused front-end: every block does hist share + float4 w1 share
    k_front<<<FRONT_BLOCKS, 256, 0, stream>>>(basis1, comp1, w1, edge_index, cnt_i);

    // CSR offsets in one block (+ w2 piggyback)
    k_scan<<<1, 1024, 0, stream>>>(cnt_i, off, cursor, basis2, comp2, w2);

    // bucket scatter (XCD-sliced)
    {
        const int chunks = (E_EDGES + 255) / 256;  // 6250
        k_bucket<<<chunks * NSLICE, 256, 0, stream>>>(edge_index, edge_type, cursor, rec);
    }

    // layer 1 (atomic-free) fused with relu/root/bias
    k_agg1x<<<N_NODES / 4, 256, 0, stream>>>(rec, off, w1, root1, bias1, x);

    // layer 2 (atomic-free) fused with root2 matvec + log_softmax
    k_agg2out<<<N_NODES / 4, 256, 0, stream>>>(rec, off, x, w2, root2, bias2, out);
}

// Round 9
// 451.124 us; speedup vs baseline: 1.2081x; 1.2081x over previous
//
#include <hip/hip_runtime.h>
#include <math.h>

// Problem constants (fixed by the reference)
#define N_NODES 50000
#define E_EDGES 1600000
#define R_REL   50
#define B_BAS   30
#define H_DIM   16
#define C_DIM   4
#define NH      (N_NODES * H_DIM)
#define NH2     (NH / 2)                 // 400,000 float2 columns

// dst slicing for XCD-local scatter writes in k_bucket
#define NSLICE      8
#define SLICE_NODES (N_NODES / NSLICE)   // 6250

// k_front geometry: 1563 blocks x 256 threads; each thread owns 2 consecutive
// (n,h) columns (float2). Round-7 scalar = 101us @ 2.6TB/s (48 VGPR, occ 43%);
// round-8 float4 = 150us (128 VGPR, occ 17% -- bv[30]x4 killed occupancy).
// float2 is the middle point: 60 VGPR for bv, ~6 waves/SIMD, 512B/wave-inst.
#define FRONT_BLOCKS    ((NH2 + 255) / 256)        // 1563
#define EDGES_PER_FRONT 1024                       // 1563*1024 >= E

// ---------------------------------------------------------------------------
// k_front: fused w1 precompute + dst histogram.
//   w1[r][n][h] = sum_b comp1[r][b]*basis1[b][n][h]
// comp1 read directly (thread-uniform -> s_load, SGPR operand to v_fmac).
// ---------------------------------------------------------------------------
__global__ __launch_bounds__(256) void k_front(const float* __restrict__ basis1,
                                               const float* __restrict__ comp1,
                                               float* __restrict__ w1,
                                               const int* __restrict__ ei,
                                               int* __restrict__ cnt_i) {
    // ---- histogram share: fire-and-forget atomics, 1024 edges/block ----
    {
        const int ebase = blockIdx.x * EDGES_PER_FRONT;
#pragma unroll
        for (int i = 0; i < 4; ++i) {
            const int e = ebase + threadIdx.x + i * 256;
            if (e < E_EDGES)
                atomicAdd(&cnt_i[ei[E_EDGES + e]], 1);
        }
    }

    // ---- w1 share: one float2 column-pair per thread ----
    const int idx2 = blockIdx.x * 256 + threadIdx.x;
    if (idx2 >= NH2) return;

    float2 bv[B_BAS];
#pragma unroll
    for (int b = 0; b < B_BAS; ++b)
        bv[b] = *(const float2*)(basis1 + (size_t)b * NH + idx2 * 2);

    for (int r = 0; r < R_REL; ++r) {
        float2 acc = {0.f, 0.f};
#pragma unroll
        for (int b = 0; b < B_BAS; ++b) {
            const float c = comp1[r * B_BAS + b];
            acc.x += c * bv[b].x;
            acc.y += c * bv[b].y;
        }
        *(float2*)(w1 + (size_t)r * NH + idx2 * 2) = acc;
    }
}

// ---------------------------------------------------------------------------
// CSR build step 2a: per-block exclusive scan of counts; block totals to bsum
// ---------------------------------------------------------------------------
__global__ __launch_bounds__(256) void k_scan_part(const int* __restrict__ cnt_i,
                                                   int* __restrict__ part,
                                                   int* __restrict__ bsum) {
    const int i = blockIdx.x * 256 + threadIdx.x;
    const int lane = threadIdx.x & 63;
    const int wid = threadIdx.x >> 6;
    const int v = (i < N_NODES) ? cnt_i[i] : 0;
    int s = v;
#pragma unroll
    for (int d = 1; d < 64; d <<= 1) {
        int t = __shfl_up(s, d, 64);
        if (lane >= d) s += t;
    }
    __shared__ int wsum[4];
    if (lane == 63) wsum[wid] = s;
    __syncthreads();
    int woff = 0;
    for (int w = 0; w < wid; ++w) woff += wsum[w];
    if (i < N_NODES) part[i] = s - v + woff;
    if (threadIdx.x == 255) bsum[blockIdx.x] = woff + s;  // block total
}

// ---------------------------------------------------------------------------
// CSR build step 2b: exclusive scan of the 196 block totals (single block).
// Also computes w2 (tiny, independent) to keep it off other kernels.
// ---------------------------------------------------------------------------
__global__ __launch_bounds__(256) void k_scan_tops(const int* __restrict__ bsum,
                                                   int* __restrict__ boff,
                                                   const float* __restrict__ basis2,
                                                   const float* __restrict__ comp2,
                                                   float* __restrict__ w2) {
    const int NB = (N_NODES + 255) / 256;  // 196
    const int lane = threadIdx.x & 63;
    const int wid = threadIdx.x >> 6;
    const int v = (threadIdx.x < NB) ? bsum[threadIdx.x] : 0;
    int s = v;
#pragma unroll
    for (int d = 1; d < 64; d <<= 1) {
        int t = __shfl_up(s, d, 64);
        if (lane >= d) s += t;
    }
    __shared__ int wsum[4];
    if (lane == 63) wsum[wid] = s;
    __syncthreads();
    int woff = 0;
    for (int w = 0; w < wid; ++w) woff += wsum[w];
    if (threadIdx.x < NB) boff[threadIdx.x] = s - v + woff;

    // w2[r][h][c] = sum_b comp2[r][b] * basis2[b][h][c]   (3200 outputs)
    const int HC = H_DIM * C_DIM;  // 64
    for (int idx = threadIdx.x; idx < R_REL * HC; idx += 256) {
        const int r = idx / HC;
        const int hc = idx % HC;
        float acc = 0.f;
#pragma unroll
        for (int b = 0; b < B_BAS; ++b)
            acc += comp2[r * B_BAS + b] * basis2[b * HC + hc];
        w2[idx] = acc;
    }
}

// ---------------------------------------------------------------------------
// CSR build step 2c: combine -> off[] and a working cursor[] copy
// ---------------------------------------------------------------------------
__global__ __launch_bounds__(256) void k_scan_add(const int* __restrict__ part,
                                                  const int* __restrict__ boff,
                                                  int* __restrict__ off,
                                                  int* __restrict__ cursor) {
    const int i = blockIdx.x * 256 + threadIdx.x;
    if (i < N_NODES) {
        const int o = part[i] + boff[blockIdx.x];
        off[i] = o;
        cursor[i] = o;
    }
    if (i == 0) off[N_NODES] = E_EDGES;
}

// ---------------------------------------------------------------------------
// CSR build step 3 (XCD-sliced): scatter packed (src | et<<16) records into
// dst buckets. blockIdx = chunk*8 + slice; a block only handles edges whose
// dst is in its slice's 6250-node range (blockIdx%8 ~ XCD -> rec slice writes
// coalesce in one XCD's L2). Streaming ei/et reads are non-temporal so they
// don't evict the dirty rec lines before neighbors coalesce into them.
// ---------------------------------------------------------------------------
__global__ __launch_bounds__(256) void k_bucket(const int* __restrict__ ei,
                                                const int* __restrict__ et,
                                                int* __restrict__ cursor,
                                                unsigned* __restrict__ rec) {
    const int chunk = blockIdx.x >> 3;
    const int slice = blockIdx.x & (NSLICE - 1);
    const int lo = slice * SLICE_NODES;

    const int e = chunk * 256 + threadIdx.x;
    if (e >= E_EDGES) return;
    const int dst = __builtin_nontemporal_load(&ei[E_EDGES + e]);
    if ((unsigned)(dst - lo) >= (unsigned)SLICE_NODES) return;

    const int src = __builtin_nontemporal_load(&ei[e]);
    const int r = __builtin_nontemporal_load(&et[e]);
    const int pos = atomicAdd(&cursor[dst], 1);
    rec[pos] = (unsigned)src | ((unsigned)r << 16);
}

// ---------------------------------------------------------------------------
// k_agg1x: atomic-free layer-1 aggregation fused with x-epilogue.
// One wave per dst; lanes = (sub=lane>>4) edge-slot x (h=lane&15).
// x[dst][h] = relu( mean_e w1[et][src][h] + root1 + bias1 )
// ---------------------------------------------------------------------------
__global__ __launch_bounds__(256) void k_agg1x(const unsigned* __restrict__ rec,
                                               const int* __restrict__ off,
                                               const float* __restrict__ w1,
                                               const float* __restrict__ root1,
                                               const float* __restrict__ bias1,
                                               float* __restrict__ x) {
    const int wid = threadIdx.x >> 6;
    const int lane = threadIdx.x & 63;
    const int dst = blockIdx.x * 4 + wid;   // grid = 12500, 4 waves/block
    const int h = lane & 15;
    const int sub = lane >> 4;
    const int e0 = off[dst], e1 = off[dst + 1];

    float acc = 0.f;
    for (int e = e0 + sub; e < e1; e += 4) {
        const unsigned p = rec[e];
        const int src = (int)(p & 0xFFFFu);
        const int r = (int)(p >> 16);
        acc += w1[(size_t)r * NH + src * H_DIM + h];
    }
    acc += __shfl_xor(acc, 16, 64);
    acc += __shfl_xor(acc, 32, 64);

    if (sub == 0) {
        const float c = fmaxf((float)(e1 - e0), 1.f);
        const float v = acc / c + root1[dst * H_DIM + h] + bias1[h];
        x[dst * H_DIM + h] = fmaxf(v, 0.f);
    }
}

// ---------------------------------------------------------------------------
// k_agg2out: atomic-free layer-2 aggregation fused with root2 matvec and
// log_softmax. One wave per dst; per edge-slot 16 lanes each do 4 FMAs.
// ---------------------------------------------------------------------------
__global__ __launch_bounds__(256) void k_agg2out(const unsigned* __restrict__ rec,
                                                 const int* __restrict__ off,
                                                 const float* __restrict__ x,
                                                 const float* __restrict__ w2,
                                                 const float* __restrict__ root2,
                                                 const float* __restrict__ bias2,
                                                 float* __restrict__ out) {
    const int wid = threadIdx.x >> 6;
    const int lane = threadIdx.x & 63;
    const int dst = blockIdx.x * 4 + wid;
    const int h = lane & 15;
    const int sub = lane >> 4;
    const int e0 = off[dst], e1 = off[dst + 1];

    float a0 = 0.f, a1 = 0.f, a2 = 0.f, a3 = 0.f;
    for (int e = e0 + sub; e < e1; e += 4) {
        const unsigned p = rec[e];
        const int src = (int)(p & 0xFFFFu);
        const int r = (int)(p >> 16);
        const float xv = x[src * H_DIM + h];
        const float4 w = *(const float4*)(w2 + r * (H_DIM * C_DIM) + h * C_DIM);
        a0 += xv * w.x; a1 += xv * w.y; a2 += xv * w.z; a3 += xv * w.w;
    }
    // reduce over all 64 lanes (sums over both h and edge-slot)
#pragma unroll
    for (int d = 1; d < 64; d <<= 1) {
        a0 += __shfl_xor(a0, d, 64);
        a1 += __shfl_xor(a1, d, 64);
        a2 += __shfl_xor(a2, d, 64);
        a3 += __shfl_xor(a3, d, 64);
    }

    if (lane == 0) {
        const float c = fmaxf((float)(e1 - e0), 1.f);
        float y0 = a0 / c + bias2[0];
        float y1 = a1 / c + bias2[1];
        float y2 = a2 / c + bias2[2];
        float y3 = a3 / c + bias2[3];
#pragma unroll
        for (int hh = 0; hh < H_DIM; ++hh) {
            const float xv = x[dst * H_DIM + hh];
            const float4 w = *(const float4*)(root2 + hh * C_DIM);
            y0 += xv * w.x; y1 += xv * w.y; y2 += xv * w.z; y3 += xv * w.w;
        }
        const float m = fmaxf(fmaxf(y0, y1), fmaxf(y2, y3));
        const float s = expf(y0 - m) + expf(y1 - m) + expf(y2 - m) + expf(y3 - m);
        const float lse = m + logf(s);
        out[dst * 4 + 0] = y0 - lse;
        out[dst * 4 + 1] = y1 - lse;
        out[dst * 4 + 2] = y2 - lse;
        out[dst * 4 + 3] = y3 - lse;
    }
}

// ---------------------------------------------------------------------------
extern "C" void kernel_launch(void* const* d_in, const int* in_sizes, int n_in,
                              void* d_out, int out_size, void* d_ws, size_t ws_size,
                              hipStream_t stream) {
    const int*   edge_index = (const int*)d_in[0];   // [2, E]
    const int*   edge_type  = (const int*)d_in[1];   // [E]
    // d_in[2] = edge_norm (unused by reference)
    const float* basis1 = (const float*)d_in[3];     // [B, N, H]
    const float* comp1  = (const float*)d_in[4];     // [R, B]
    const float* root1  = (const float*)d_in[5];     // [N, H]
    const float* bias1  = (const float*)d_in[6];     // [H]
    const float* basis2 = (const float*)d_in[7];     // [B, H, C]
    const float* comp2  = (const float*)d_in[8];     // [R, B]
    const float* root2  = (const float*)d_in[9];     // [H, C]
    const float* bias2  = (const float*)d_in[10];    // [C]

    float* out = (float*)d_out;

    // ---- workspace layout (16B aligned blocks) ----
    char* ws = (char*)d_ws;
    size_t o = 0;
    auto take = [&](size_t bytes) { char* p = ws + o; o += (bytes + 15) & ~(size_t)15; return p; };

    float*    w1     = (float*)   take((size_t)R_REL * NH * sizeof(float));   // 160.0 MB
    unsigned* rec    = (unsigned*)take((size_t)E_EDGES * sizeof(unsigned));   //   6.4 MB
    float*    x      = (float*)   take((size_t)NH * sizeof(float));           //   3.2 MB
    int*      part   = (int*)x;   // alias: part dead before x is written
    int*      off    = (int*)     take((size_t)(N_NODES + 1) * sizeof(int));
    int*      cnt_i  = (int*)     take((size_t)N_NODES * sizeof(int));
    int*      cursor = (int*)     take((size_t)N_NODES * sizeof(int));
    float*    w2     = (float*)   take((size_t)R_REL * H_DIM * C_DIM * sizeof(float));
    int*      bsum   = (int*)     take(256 * sizeof(int));
    int*      boff   = (int*)     take(256 * sizeof(int));
    (void)ws_size;

    const int NB = (N_NODES + 255) / 256;  // 196 scan blocks

    // zero the histogram (ws is poisoned 0xAA before every timed call)
    hipMemsetAsync(cnt_i, 0, (size_t)N_NODES * sizeof(int), stream);

    // fused front-end: every block does hist share + float2 w1 share
    k_front<<<FRONT_BLOCKS, 256, 0, stream>>>(basis1, comp1, w1, edge_index, cnt_i);

    // CSR build: scan (+w2 piggyback) -> bucket (XCD-sliced scatter)
    k_scan_part<<<NB, 256, 0, stream>>>(cnt_i, part, bsum);
    k_scan_tops<<<1, 256, 0, stream>>>(bsum, boff, basis2, comp2, w2);
    k_scan_add<<<NB, 256, 0, stream>>>(part, boff, off, cursor);
    {
        const int chunks = (E_EDGES + 255) / 256;  // 6250
        k_bucket<<<chunks * NSLICE, 256, 0, stream>>>(edge_index, edge_type, cursor, rec);
    }

    // layer 1 (atomic-free) fused with relu/root/bias
    k_agg1x<<<N_NODES / 4, 256, 0, stream>>>(rec, off, w1, root1, bias1, x);

    // layer 2 (atomic-free) fused with root2 matvec + log_softmax
    k_agg2out<<<N_NODES / 4, 256, 0, stream>>>(rec, off, x, w2, root2, bias2, out);
}